// Round 1
// baseline (120.647 us; speedup 1.0000x reference)
//
#include <hip/hip_runtime.h>

// TopKActivation: out = relu(x) masked to the row-wise top-k of relu(x).
// One 256-thread block per row; row held entirely in registers (16 elem/thread).
// Threshold via 4x8-bit radix select on float bits (positive floats sort as uints),
// restricted to candidates > 1.5f when that set is >= k (guarded; fallback is exact).
// Ties at the threshold resolved stably (lowest column index first) to match
// XLA top_k semantics.

constexpr int ROW_LEN = 4096;
constexpr int TPB     = 256;
constexpr int EPT     = ROW_LEN / TPB; // 16 elements per thread

__global__ __launch_bounds__(TPB, 4)
void topk_relu_kernel(const float* __restrict__ x, const int* __restrict__ kptr,
                      float* __restrict__ out, int rows)
{
    __shared__ int hist[256];
    __shared__ int wtot[4];
    __shared__ int sel_digit;
    __shared__ int sel_kk;
    __shared__ int sel_flag;

    const int row = blockIdx.x;
    if (row >= rows) return;
    const int tid  = threadIdx.x;
    const int lane = tid & 63;
    const int wid  = tid >> 6;

    const size_t rowbase = (size_t)row * ROW_LEN + (size_t)tid * EPT;
    const float4* __restrict__ xv = (const float4*)(x + rowbase);

    // ---- load row (blocked: thread t owns cols [16t, 16t+16) => thread order == col order) ----
    unsigned int key[EPT];
#pragma unroll
    for (int j = 0; j < EPT / 4; ++j) {
        float4 v = xv[j];
        key[4 * j + 0] = __float_as_uint(fmaxf(v.x, 0.0f));
        key[4 * j + 1] = __float_as_uint(fmaxf(v.y, 0.0f));
        key[4 * j + 2] = __float_as_uint(fmaxf(v.z, 0.0f));
        key[4 * j + 3] = __float_as_uint(fmaxf(v.w, 0.0f));
    }

    int k = *kptr;
    if (k > ROW_LEN) k = ROW_LEN;

    // ---- guarded prefilter: count elements > 1.5f (no atomics) ----
    const unsigned int KPRE_BITS = 0x3FC00000u; // bits of 1.5f
    int c1 = 0;
#pragma unroll
    for (int j = 0; j < EPT; ++j) c1 += (key[j] > KPRE_BITS) ? 1 : 0;
#pragma unroll
    for (int d = 1; d < 64; d <<= 1) c1 += __shfl_down(c1, d);
    if (lane == 0) wtot[wid] = c1;
    __syncthreads();
    const int cpre = wtot[0] + wtot[1] + wtot[2] + wtot[3];
    // If enough candidates above 1.5, restrict the select to them (cuts LDS atomics ~8x).
    // Otherwise fall back to all positive elements (exact, slower; never hit for N(0,1)).
    const unsigned int kpre = (cpre >= k) ? KPRE_BITS : 0u;

    // ---- 4-pass radix select, 8 bits per pass, MSB first ----
    int kk = k;               // how many still needed within current prefix group
    unsigned int prefix = 0;  // selected high bits so far
    int t0flag = 0;           // set if fewer candidates than k (threshold would be 0)

    for (int p = 0; p < 4; ++p) {
        const int shift = 24 - 8 * p;
        hist[tid] = 0;
        if (tid == 0) sel_flag = 0;
        __syncthreads();
#pragma unroll
        for (int j = 0; j < EPT; ++j) {
            const unsigned int kj = key[j];
            if (kj > kpre && (p == 0 || (kj >> (shift + 8)) == prefix))
                atomicAdd(&hist[(kj >> shift) & 255u], 1);
        }
        __syncthreads();
        if (tid < 64) {
            // wave 0: descending cumulative over 256 bins, 4 bins/lane
            const int b0 = tid * 4;
            const int h0 = hist[b0 + 0], h1 = hist[b0 + 1];
            const int h2 = hist[b0 + 2], h3 = hist[b0 + 3];
            const int lsum = h0 + h1 + h2 + h3;
            int suf = lsum; // inclusive suffix sum over lanes: sum of bins >= b0
#pragma unroll
            for (int d = 1; d < 64; d <<= 1) {
                int v = __shfl_down(suf, d);
                if (lane < 64 - d) suf += v;
            }
            const unsigned long long m = __ballot(suf >= kk);
            if (m == 0ull) {
                if (lane == 0) sel_flag = 1; // not enough candidates: threshold is 0
            } else {
                const int L = 63 - __clzll(m); // highest lane whose suffix still >= kk
                if (lane == L) {
                    int cum = suf - lsum; // count of keys in bins > b0+3 (strictly above this lane)
                    const int hh[4] = {h0, h1, h2, h3};
#pragma unroll
                    for (int b = 3; b >= 0; --b) {
                        const int h = hh[b];
                        if (cum + h >= kk) { sel_digit = b0 + b; sel_kk = kk - cum; break; }
                        cum += h;
                    }
                }
            }
        }
        __syncthreads();
        if (sel_flag) { t0flag = 1; break; }
        prefix = (prefix << 8) | (unsigned int)sel_digit;
        kk = sel_kk;
        __syncthreads(); // protect sel_* reads from next pass's re-init
    }

    unsigned int T;
    int need;
    if (t0flag) { T = 0u; need = 0; }   // threshold 0: keep all positives; ties at 0 emit 0 anyway
    else        { T = prefix; need = kk; } // need = # of ==T elements to keep (stable, lowest index)

    // ---- stable rank of ==T elements in ascending column order ----
    int eqc = 0;
#pragma unroll
    for (int j = 0; j < EPT; ++j) eqc += (key[j] == T) ? 1 : 0;
    int inc = eqc;
#pragma unroll
    for (int d = 1; d < 64; d <<= 1) {
        int v = __shfl_up(inc, d);
        if (lane >= d) inc += v;
    }
    if (lane == 63) wtot[wid] = inc;
    __syncthreads();
    int base = 0;
    for (int w = 0; w < wid; ++w) base += wtot[w];
    int r = base + (inc - eqc); // exclusive prefix of eq-count in column order

    // ---- emit ----
    float4* __restrict__ ov = (float4*)(out + rowbase);
#pragma unroll
    for (int j = 0; j < EPT / 4; ++j) {
        float4 v;
        float f[4];
#pragma unroll
        for (int c = 0; c < 4; ++c) {
            const unsigned int kj = key[4 * j + c];
            bool keep;
            if (kj == T) { keep = (r < need); ++r; }
            else         { keep = (kj > T); }
            f[c] = keep ? __uint_as_float(kj) : 0.0f;
        }
        v.x = f[0]; v.y = f[1]; v.z = f[2]; v.w = f[3];
        ov[j] = v;
    }
}

extern "C" void kernel_launch(void* const* d_in, const int* in_sizes, int n_in,
                              void* d_out, int out_size, void* d_ws, size_t ws_size,
                              hipStream_t stream)
{
    const float* x    = (const float*)d_in[0];
    const int*   kptr = (const int*)d_in[1];
    float*       out  = (float*)d_out;
    const int rows = in_sizes[0] / ROW_LEN;
    topk_relu_kernel<<<rows, TPB, 0, stream>>>(x, kptr, out, rows);
}